// Round 5
// baseline (153.172 us; speedup 1.0000x reference)
//
#include <hip/hip_runtime.h>

#define D 32
#define CAP 256            // per-node adjacency list capacity (fast path)
#define CSTRIDE 16         // counter stride in ints (64 B) to spread line contention

// ===========================================================================
// K1: build undirected CSR WITH duplicates (dedup happens in the gather).
// 2 atomicAdd + 2 stores per edge. Stores past CAP are dropped; the count
// keeps growing so the gather can detect overflow and take the exact path.
// ===========================================================================
__global__ void gnn_csr_build(const int* __restrict__ src,
                              const int* __restrict__ dst,
                              int* __restrict__ cnt,
                              int* __restrict__ list, int E) {
    int e = blockIdx.x * blockDim.x + threadIdx.x;
    if (e >= E) return;
    int s = src[e];
    int d = dst[e];
    int p = atomicAdd(&cnt[(size_t)d * CSTRIDE], 1);
    if (p < CAP) list[(size_t)d * CAP + p] = s;
    int q = atomicAdd(&cnt[(size_t)s * CSTRIDE], 1);
    if (q < CAP) list[(size_t)s * CAP + q] = d;
}

// ===========================================================================
// K2: gather + fused update. 1 wave per node, 4 nodes per block.
// Dedup via per-wave 2 KB LDS bitmap: lane atomicOr's its neighbor bit and
// keeps the entry only if the bit was clear (handles duplicate edges,
// (a,b)/(b,a) pairs, and self-loops exactly like the 0/1 adjacency).
// ===========================================================================
__global__ __launch_bounds__(256) void gnn_gather_update(
        const int* __restrict__ cnt,
        const int* __restrict__ list,
        const int* __restrict__ src,      // for overflow fallback
        const int* __restrict__ dst,
        int E,
        const float* __restrict__ x,
        float* __restrict__ out,
        const float* __restrict__ W_agg,
        const float* __restrict__ b_agg,
        const float* __restrict__ W_upd,
        const float* __restrict__ b_upd) {
    __shared__ float sWa[D][D + 1];
    __shared__ float sWu[D][D + 1];
    __shared__ float sb[D];
    __shared__ float sx[4][D];
    __shared__ float sm[4][D];
    __shared__ unsigned int sbit[4][512];   // 16384-bit dedup bitmap per wave
    __shared__ int slist[4][64];            // compacted chunk of kept neighbors

    int t = threadIdx.x;
    for (int i = t; i < D * D; i += 256) {
        sWa[i >> 5][i & 31] = W_agg[i];
        sWu[i >> 5][i & 31] = W_upd[i];
    }
    if (t < D) sb[t] = b_agg[t] + b_upd[t];

    int lane = t & 63;
    int wv   = t >> 6;
    int dim  = lane & 31;
    int half = lane >> 5;
    size_t node = (size_t)blockIdx.x * 4 + wv;

    if (lane < D) sx[wv][lane] = x[node * D + lane];

    // clear my wave's dedup bitmap (512 dwords)
#pragma unroll
    for (int i = 0; i < 8; ++i) sbit[wv][i * 64 + lane] = 0u;

    int deg = cnt[node * CSTRIDE];
    float acc = 0.f;

    if (deg <= CAP) {
        const int* ml = list + node * CAP;
        for (int base = 0; base < deg; base += 64) {
            int idx = -1, keep = 0;
            if (base + lane < deg) {
                idx = ml[base + lane];
                unsigned int old = atomicOr(&sbit[wv][idx >> 5], 1u << (idx & 31));
                keep = !((old >> (idx & 31)) & 1u);
            }
            // wave prefix-sum over keep -> compact positions
            int pre = keep;
#pragma unroll
            for (int off = 1; off < 64; off <<= 1) {
                int v = __shfl_up(pre, off, 64);
                if (lane >= off) pre += v;
            }
            int ckn = __shfl(pre, 63, 64);
            if (keep) slist[wv][pre - 1] = idx;
            __asm__ __volatile__("s_waitcnt lgkmcnt(0)" ::: "memory");

            // ILP-batched gather over this chunk (halves interleave, 4 loads in flight)
            int j = half;
            for (; j + 8 <= ckn; j += 8) {
                int c0 = slist[wv][j + 0];
                int c1 = slist[wv][j + 2];
                int c2 = slist[wv][j + 4];
                int c3 = slist[wv][j + 6];
                float v0 = x[(size_t)c0 * D + dim];
                float v1 = x[(size_t)c1 * D + dim];
                float v2 = x[(size_t)c2 * D + dim];
                float v3 = x[(size_t)c3 * D + dim];
                acc += v0; acc += v1; acc += v2; acc += v3;
            }
            for (; j < ckn; j += 2)
                acc += x[(size_t)slist[wv][j] * D + dim];
        }
    } else {
        // exact overflow fallback: scan the whole edge list with LDS dedup
        for (int base = 0; base < E; base += 64) {
            int e = base + lane;
            int nbr = -1, keep = 0;
            if (e < E) {
                int s = src[e], d = dst[e];
                if (s == (int)node)      nbr = d;
                else if (d == (int)node) nbr = s;
            }
            if (nbr >= 0) {
                unsigned int old = atomicOr(&sbit[wv][nbr >> 5], 1u << (nbr & 31));
                keep = !((old >> (nbr & 31)) & 1u);
            }
            int pre = keep;
#pragma unroll
            for (int off = 1; off < 64; off <<= 1) {
                int v = __shfl_up(pre, off, 64);
                if (lane >= off) pre += v;
            }
            int ckn = __shfl(pre, 63, 64);
            if (keep) slist[wv][pre - 1] = nbr;
            __asm__ __volatile__("s_waitcnt lgkmcnt(0)" ::: "memory");
            for (int j = half; j < ckn; j += 2)
                acc += x[(size_t)slist[wv][j] * D + dim];
        }
    }

    acc += __shfl_xor(acc, 32, 64);       // combine the two halves
    if (lane < D) sm[wv][lane] = acc;
    __syncthreads();

    // fused epilogue: out = b + x*W_upd^T + msg*W_agg^T
    if (t < 128) {
        int ns = t >> 5;
        int o  = t & 31;
        float r = sb[o];
#pragma unroll
        for (int k = 0; k < D; ++k)
            r += sx[ns][k] * sWu[o][k] + sm[ns][k] * sWa[o][k];
        out[((size_t)blockIdx.x * 4 + ns) * D + o] = r;
    }
}

// ===========================================================================
// FALLBACK PATH (small ws): hash-dedup + scattered atomics (round-1 code).
// ===========================================================================
#define HASH_BITS 20
#define HASH_SIZE (1u << HASH_BITS)
#define EMPTY_KEY 0xFFFFFFFFu

__global__ void gnn_edge_scatter(const int* __restrict__ src,
                                 const int* __restrict__ dst,
                                 const float* __restrict__ x,
                                 float* __restrict__ msg,
                                 unsigned int* __restrict__ htab,
                                 int E) {
    int e = blockIdx.x * blockDim.x + threadIdx.x;
    if (e >= E) return;
    int s = src[e];
    int d = dst[e];
    int a = s < d ? s : d;
    int b = s < d ? d : s;
    unsigned int key = ((unsigned int)a << 14) | (unsigned int)b;
    unsigned int h = (key * 2654435761u) >> (32 - HASH_BITS);
    bool inserted;
    for (;;) {
        unsigned int prev = atomicCAS(&htab[h], EMPTY_KEY, key);
        if (prev == EMPTY_KEY) { inserted = true; break; }
        if (prev == key)       { inserted = false; break; }
        h = (h + 1) & (HASH_SIZE - 1);
    }
    if (!inserted) return;
    const float* xs = x + (size_t)s * D;
    const float* xd = x + (size_t)d * D;
    if (s == d) {
        float* mrow = msg + (size_t)s * D;
#pragma unroll
        for (int i = 0; i < D; ++i) atomicAdd(&mrow[i], xs[i]);
    } else {
        float* ms = msg + (size_t)s * D;
        float* md = msg + (size_t)d * D;
#pragma unroll
        for (int i = 0; i < D; ++i) {
            atomicAdd(&ms[i], xd[i]);
            atomicAdd(&md[i], xs[i]);
        }
    }
}

__global__ __launch_bounds__(256) void gnn_update(
        const float* __restrict__ x,
        float* __restrict__ out,
        const float* __restrict__ W_agg,
        const float* __restrict__ b_agg,
        const float* __restrict__ W_upd,
        const float* __restrict__ b_upd) {
    __shared__ float sWa[D][D + 1];
    __shared__ float sWu[D][D + 1];
    __shared__ float sb[D];
    __shared__ float sx[8][D];
    __shared__ float sm[8][D];
    int t = threadIdx.x;
    for (int i = t; i < D * D; i += 256) {
        sWa[i >> 5][i & 31] = W_agg[i];
        sWu[i >> 5][i & 31] = W_upd[i];
    }
    if (t < D) sb[t] = b_agg[t] + b_upd[t];
    int g = t >> 5, o = t & 31;
    size_t node = (size_t)blockIdx.x * 8 + g;
    sx[g][o] = x[node * D + o];
    sm[g][o] = out[node * D + o];
    __syncthreads();
    float acc = sb[o];
#pragma unroll
    for (int k = 0; k < D; ++k) {
        acc += sx[g][k] * sWu[o][k];
        acc += sm[g][k] * sWa[o][k];
    }
    out[node * D + o] = acc;
}

// ===========================================================================

extern "C" void kernel_launch(void* const* d_in, const int* in_sizes, int n_in,
                              void* d_out, int out_size, void* d_ws, size_t ws_size,
                              hipStream_t stream) {
    const float* x      = (const float*)d_in[0];
    const int*   eidx   = (const int*)d_in[1];
    const float* W_agg  = (const float*)d_in[2];
    const float* b_agg  = (const float*)d_in[3];
    const float* W_upd  = (const float*)d_in[4];
    const float* b_upd  = (const float*)d_in[5];
    float* out = (float*)d_out;

    const int E = in_sizes[1] / 2;
    const int N = in_sizes[0] / D;
    const int* src = eidx;
    const int* dst = eidx + E;

    const size_t cnt_bytes  = (size_t)N * CSTRIDE * sizeof(int);   // 1 MiB
    const size_t list_bytes = (size_t)N * CAP * sizeof(int);       // 16 MiB

    if (ws_size >= cnt_bytes + list_bytes) {
        int* cnt  = (int*)d_ws;
        int* list = (int*)((char*)d_ws + cnt_bytes);
        hipMemsetAsync(cnt, 0, cnt_bytes, stream);
        gnn_csr_build<<<(E + 255) / 256, 256, 0, stream>>>(src, dst, cnt, list, E);
        gnn_gather_update<<<N / 4, 256, 0, stream>>>(cnt, list, src, dst, E,
                                                     x, out, W_agg, b_agg,
                                                     W_upd, b_upd);
    } else {
        unsigned int* htab = (unsigned int*)d_ws;
        hipMemsetAsync(out, 0, (size_t)N * D * sizeof(float), stream);
        hipMemsetAsync(htab, 0xFF, (size_t)HASH_SIZE * sizeof(unsigned int), stream);
        gnn_edge_scatter<<<(E + 255) / 256, 256, 0, stream>>>(src, dst, x, out, htab, E);
        gnn_update<<<N / 8, 256, 0, stream>>>(x, out, W_agg, b_agg, W_upd, b_upd);
    }
}